// Round 12
// baseline (422.269 us; speedup 1.0000x reference)
//
#include <hip/hip_runtime.h>
#include <cstdint>
#include <cstddef>

#define NY 8400
#define NR 300
#define NF 8700
#define STHR 0.5f
#define ITHR 0.5f
#define NSPLIT 8
#define NPAD 8704
#define NCHMAX 136
#define WAVES 8
#define NCHPAD 137   // per-copy u64 stride (padded)

// lgkm-only barrier: orders LDS ops across waves WITHOUT draining outstanding
// global loads (no vmcnt(0)). Safe here: no cross-wave global communication in
// the scan loop; speculative loads are consumed via compiler-inserted vmcnt
// waits at their use, one word later. sched_barrier fences reordering (rule #18).
#define BARX() do {                                             \
    __builtin_amdgcn_sched_barrier(0);                          \
    asm volatile("s_waitcnt lgkmcnt(0)" ::: "memory");          \
    __builtin_amdgcn_s_barrier();                               \
    __builtin_amdgcn_sched_barrier(0);                          \
} while (0)

// IOU with explicit-rounding ops so fp-contraction cannot perturb the
// iou > 0.5 comparison vs the numpy fp32 reference.
__device__ __forceinline__ float iou_pair(float4 a, float4 b) {
    float ltx = fmaxf(a.x, b.x);
    float lty = fmaxf(a.y, b.y);
    float rbx = fminf(a.z, b.z);
    float rby = fminf(a.w, b.w);
    float w = fmaxf(__fsub_rn(rbx, ltx), 0.0f);
    float h = fmaxf(__fsub_rn(rby, lty), 0.0f);
    float inter  = __fmul_rn(w, h);
    float area_a = __fmul_rn(__fsub_rn(a.z, a.x), __fsub_rn(a.w, a.y));
    float area_b = __fmul_rn(__fsub_rn(b.z, b.x), __fsub_rn(b.w, b.y));
    float denom  = __fsub_rn(__fadd_rn(area_a, area_b), inter);
    float d = denom > 0.0f ? denom : 1.0f;
    return __fdiv_rn(inter, d);
}

__global__ void prep_yolo(const float* __restrict__ y,
                          float* __restrict__ xyxy, float* __restrict__ conf, int N) {
    int i = blockIdx.x * blockDim.x + threadIdx.x;
    if (i >= N) return;
    float cx = y[0 * N + i], cy = y[1 * N + i];
    float w  = y[2 * N + i], h  = y[3 * N + i];
    float c  = y[4 * N + i];
    xyxy[i * 4 + 0] = cx - w * 0.5f;
    xyxy[i * 4 + 1] = cy - h * 0.5f;
    xyxy[i * 4 + 2] = cx + w * 0.5f;
    xyxy[i * 4 + 3] = cy + h * 0.5f;
    conf[i] = c;
}

__global__ void prep_rtdetr(const float* __restrict__ r,
                            float* __restrict__ xyxy, float* __restrict__ conf, int N) {
    __shared__ float red[512];
    int t = threadIdx.x;
    float m = -INFINITY;
    for (int i = t; i < N; i += blockDim.x) m = fmaxf(m, r[i * 5 + 4]);
    red[t] = m;
    __syncthreads();
    for (int s = 256; s > 0; s >>= 1) {
        if (t < s) red[t] = fmaxf(red[t], red[t + s]);
        __syncthreads();
    }
    float mx = red[0];
    for (int i = t; i < N; i += blockDim.x) {
        float cx = r[i * 5 + 0], cy = r[i * 5 + 1];
        float w  = r[i * 5 + 2], h  = r[i * 5 + 3];
        float c  = r[i * 5 + 4];
        xyxy[i * 4 + 0] = cx - w * 0.5f;
        xyxy[i * 4 + 1] = cy - h * 0.5f;
        xyxy[i * 4 + 2] = cx + w * 0.5f;
        xyxy[i * 4 + 3] = cy + h * 0.5f;
        conf[i] = __fdiv_rn(c, mx);
    }
}

// Partial stable-descending rank over j-slice blockIdx.y. LDS-tiled broadcast.
__global__ void rank_partial(const float* __restrict__ conf, int* __restrict__ partial, int N) {
    __shared__ float kk[1152];
    int i  = blockIdx.x * 256 + threadIdx.x;
    int js = blockIdx.y;
    int slice = (N + NSPLIT - 1) / NSPLIT;
    int j0 = js * slice;
    int j1 = min(N, j0 + slice);
    for (int j = j0 + threadIdx.x; j < j1; j += 256) {
        float c = conf[j];
        kk[j - j0] = (c >= STHR) ? c : -1.0f;
    }
    __syncthreads();
    float ci = (i < N) ? conf[i] : 0.0f;
    float ki = (ci >= STHR) ? ci : -1.0f;
    int r = 0;
    int len = j1 - j0;
    for (int jj = 0; jj < len; ++jj) {
        float kj = kk[jj];
        int j = j0 + jj;
        r += (kj > ki) || (kj == ki && j < i);
    }
    if (i < N) partial[js * NPAD + i] = r;
}

__global__ void rank_scatter(const float* __restrict__ xyxy, const float* __restrict__ conf,
                             const int* __restrict__ partial,
                             float* __restrict__ xyxy_s, float* __restrict__ conf_s, int N) {
    int i = blockIdx.x * blockDim.x + threadIdx.x;
    if (i >= N) return;
    int rank = 0;
    #pragma unroll
    for (int js = 0; js < NSPLIT; ++js) rank += partial[js * NPAD + i];
    xyxy_s[rank * 4 + 0] = xyxy[i * 4 + 0];
    xyxy_s[rank * 4 + 1] = xyxy[i * 4 + 1];
    xyxy_s[rank * 4 + 2] = xyxy[i * 4 + 2];
    xyxy_s[rank * 4 + 3] = xyxy[i * 4 + 3];
    conf_s[rank] = conf[i];
}

// One block per row i; 4 waves stride chunks. Below-diagonal chunks zero-filled.
// Also writes diag[i] = mask[i][i>>6] (the 64x64 diagonal block words).
__global__ void nms_mask_row(const float* __restrict__ xyxy_s, uint64_t* __restrict__ mask,
                             uint64_t* __restrict__ diag, int N, int nch, int stride) {
    int i = blockIdx.x;
    int lane = threadIdx.x & 63;
    int wv   = threadIdx.x >> 6;
    float4 bi = *(const float4*)(xyxy_s + (size_t)i * 4);
    int cd = i >> 6;
    for (int c = wv; c < nch; c += 4) {
        if (c < cd) {
            if (lane == 0) mask[(size_t)i * stride + c] = 0ull;
            continue;
        }
        int j = (c << 6) + lane;
        bool bit = false;
        if (j < N && j > i) {
            float4 bj = *(const float4*)(xyxy_s + (size_t)j * 4);
            bit = iou_pair(bi, bj) > ITHR;
        }
        uint64_t m = __ballot(bit);
        if (lane == 0) {
            mask[(size_t)i * stride + c] = m;
            if (c == cd) diag[i] = m;
        }
    }
}

__device__ __forceinline__ uint64_t readlane64(uint64_t v, int k) {
    uint32_t lo = (uint32_t)__builtin_amdgcn_readlane((int)(uint32_t)v, k);
    uint32_t hi = (uint32_t)__builtin_amdgcn_readlane((int)(uint32_t)(v >> 32), k);
    return ((uint64_t)hi << 32) | lo;
}

__device__ __forceinline__ uint64_t rfl64(uint64_t v) {
    uint32_t lo = (uint32_t)__builtin_amdgcn_readfirstlane((int)(uint32_t)v);
    uint32_t hi = (uint32_t)__builtin_amdgcn_readfirstlane((int)(uint32_t)(v >> 32));
    return ((uint64_t)hi << 32) | lo;
}

// Multi-wave scan v5 = round-10 validated structure + lgkm-only barriers
// (no vmcnt drain at barriers) + 8 waves (8 rows/wave: cheaper barriers,
// half the resolver copy-OR, half the LDS RMW copies).
__global__ __launch_bounds__(512, 1)
void nms_scan_mw(const float* __restrict__ conf_s, const uint64_t* __restrict__ mask,
                 const uint64_t* __restrict__ diag, const float* __restrict__ xyxy_s,
                 float* __restrict__ out5, float* __restrict__ xf, float* __restrict__ cf,
                 int off, int N, int nch, int stride) {
    __shared__ uint64_t bmflat[WAVES * NCHPAD];
    __shared__ uint64_t keptw[NCHMAX];
    __shared__ int redcnt[WAVES];

    int tid  = threadIdx.x;
    int wv   = tid >> 6;
    int lane = tid & 63;
    bool hastail = (128 + lane) < nch;

    // zero copies + count valid, one barrier
    for (int idx = tid; idx < WAVES * NCHPAD; idx += 512) bmflat[idx] = 0ull;
    int cnt = 0;
    for (int j = tid; j < N; j += 512) cnt += (conf_s[j] >= STHR) ? 1 : 0;
    #pragma unroll
    for (int s = 32; s > 0; s >>= 1) cnt += __shfl_down(cnt, s, 64);
    if (lane == 0) redcnt[wv] = cnt;
    __syncthreads();
    int nvalid = 0;
    #pragma unroll
    for (int q = 0; q < WAVES; ++q) nvalid += redcnt[q];

    int vch = (nvalid + 63) >> 6;

    ulonglong2 sA[8], sB[8];
    uint64_t tA[8] = {0,0,0,0,0,0,0,0}, tB[8] = {0,0,0,0,0,0,0,0};
    uint64_t dgA = 0, dgB = 0;
    #pragma unroll
    for (int q = 0; q < 8; ++q) { sA[q].x = sA[q].y = 0ull; sB[q].x = sB[q].y = 0ull; }

// Triangular pruning (validated r10): rows of word c only need chunks [c, vch);
// invalid rows (>= nvalid) never kept -> skip. Skipped lanes contribute zeros.
#define ISSUE(S, CW) do {                                                     \
    int _c = (CW);                                                            \
    if (_c < vch) {                                                           \
        int base = _c << 6;                                                   \
        dg##S = diag[base + lane];                                            \
        bool pairok = (2 * lane + 1 >= _c) && (2 * lane < vch);               \
        bool tailok = hastail && (128 + lane >= _c) && (128 + lane < vch);    \
        _Pragma("unroll")                                                     \
        for (int q = 0; q < 8; ++q) {                                         \
            int row = base + (wv << 3) + q;                                   \
            bool rok = row < nvalid;                                          \
            row = row < N ? row : N - 1;                                      \
            const uint64_t* rb = mask + (size_t)row * stride;                 \
            ulonglong2 v; v.x = 0ull; v.y = 0ull;                             \
            if (pairok && rok) v = *((const ulonglong2*)rb + lane);           \
            s##S[q] = v;                                                      \
            t##S[q] = (tailok && rok) ? rb[128 + lane] : 0ull;                \
        }                                                                     \
    }                                                                         \
} while (0)

// wave 0 only: sparse greedy resolve (validated r9): only lanes whose diag
// word intersects `alive` need serial processing.
#define RESOLVE(S, CW) do {                                                   \
    int _c = (CW);                                                            \
    if (_c < vch && wv == 0) {                                                \
        int base = _c << 6;                                                   \
        uint64_t curw_v = (base + 64 > nvalid)                                \
            ? ((nvalid > base) ? (~0ull << (nvalid - base)) : ~0ull) : 0ull;  \
        _Pragma("unroll")                                                     \
        for (int q = 0; q < WAVES; ++q) curw_v |= bmflat[q * NCHPAD + _c];    \
        uint64_t alive = ~rfl64(curw_v);                                      \
        uint64_t Sset = __ballot((dg##S & alive) != 0ull) & alive;            \
        uint64_t sup = 0ull;                                                  \
        while (Sset) {                                                        \
            int k = __builtin_amdgcn_readfirstlane((int)__builtin_ctzll(Sset)); \
            uint64_t rck = readlane64(dg##S, k);                              \
            if (!((sup >> k) & 1ull)) sup |= rck;                             \
            Sset &= Sset - 1;                                                 \
            Sset &= ~sup;                                                     \
        }                                                                     \
        uint64_t kept = alive & ~sup;                                         \
        if (lane == 0) keptw[_c] = kept;                                      \
    }                                                                         \
} while (0)

#define ORPH(S, CW) do {                                                      \
    int _c = (CW);                                                            \
    if (_c < vch) {                                                           \
        uint64_t kept = keptw[_c];                                            \
        uint64_t a0 = 0, a1 = 0, at = 0;                                      \
        _Pragma("unroll")                                                     \
        for (int q = 0; q < 8; ++q) {                                         \
            uint64_t mk = 0ull - ((kept >> ((wv << 3) + q)) & 1ull);          \
            a0 |= s##S[q].x & mk; a1 |= s##S[q].y & mk; at |= t##S[q] & mk;   \
        }                                                                     \
        bmflat[wv * NCHPAD + 2 * lane]     |= a0;                             \
        bmflat[wv * NCHPAD + 2 * lane + 1] |= a1;                             \
        if (hastail) bmflat[wv * NCHPAD + 128 + lane] |= at;                  \
    }                                                                         \
} while (0)

    ISSUE(A, 0);
    for (int c = 0; c < vch; c += 2) {
        BARX();                   // prev word's ORs visible (LDS only)
        ISSUE(B, c + 1);          // speculative; consumed next word (vmcnt at use)
        RESOLVE(A, c);
        BARX();                   // keptw visible; resolver done reading copies
        ORPH(A, c);
        BARX();
        ISSUE(A, c + 2);
        RESOLVE(B, c + 1);
        BARX();
        ORPH(B, c + 1);
    }
#undef ISSUE
#undef RESOLVE
#undef ORPH

    __syncthreads();
    // fused epilogue: write rows (kept ? [box,conf] : 0)
    for (int j = tid; j < N; j += 512) {
        int w = j >> 6;
        uint64_t kw = (w < vch) ? keptw[w] : 0ull;
        bool keep = (kw >> (j & 63)) & 1ull;
        float4 b = *(const float4*)(xyxy_s + (size_t)j * 4);
        float cv = conf_s[j];
        if (out5) {
            out5[j * 5 + 0] = keep ? b.x : 0.0f;
            out5[j * 5 + 1] = keep ? b.y : 0.0f;
            out5[j * 5 + 2] = keep ? b.z : 0.0f;
            out5[j * 5 + 3] = keep ? b.w : 0.0f;
            out5[j * 5 + 4] = keep ? cv  : 0.0f;
        } else {
            int o = off + j;
            xf[o * 4 + 0] = keep ? b.x : 0.0f;
            xf[o * 4 + 1] = keep ? b.y : 0.0f;
            xf[o * 4 + 2] = keep ? b.z : 0.0f;
            xf[o * 4 + 3] = keep ? b.w : 0.0f;
            cf[o] = keep ? cv : 0.0f;
        }
    }
}

static void run_stage(const float* xyxy_in, const float* conf_in,
                      float* xyxy_s, float* conf_s, int* partial,
                      uint64_t* mask, uint64_t* diag,
                      int N, int stride, hipStream_t stream,
                      float* out5, float* xf, float* cf, int off) {
    int nch = (N + 63) / 64;
    dim3 gA((N + 255) / 256, NSPLIT);
    rank_partial<<<gA, 256, 0, stream>>>(conf_in, partial, N);
    rank_scatter<<<(N + 255) / 256, 256, 0, stream>>>(xyxy_in, conf_in, partial, xyxy_s, conf_s, N);
    nms_mask_row<<<N, 256, 0, stream>>>(xyxy_s, mask, diag, N, nch, stride);
    nms_scan_mw<<<1, 512, 0, stream>>>(conf_s, mask, diag, xyxy_s,
                                       out5, xf, cf, off, N, nch, stride);
}

extern "C" void kernel_launch(void* const* d_in, const int* in_sizes, int n_in,
                              void* d_out, int out_size, void* d_ws, size_t ws_size,
                              hipStream_t stream) {
    const float* yolo   = (const float*)d_in[0];  // (1,5,8400)
    const float* rtdetr = (const float*)d_in[1];  // (1,300,5)
    float* out = (float*)d_out;                   // (8700,5)
    float* ws  = (float*)d_ws;

    // ws layout (floats) — identical to the validated round-9/10 layout
    float* xyxy_in = ws;                 // 8700*4 = 139200 B
    float* conf_in = ws + 34800;         // 8700
    float* xyxy_s  = ws + 43500;         // 8700*4 (16B aligned)
    float* conf_s  = ws + 78300;         // 8700
    float* xyxy_f  = ws + 87000;         // 8700*4 (stage-3 input, fused concat)
    float* conf_f  = ws + 121800;        // 8700 -> ends 130500 floats = 522000 B
    uint64_t* mask = (uint64_t*)((char*)d_ws + 523088);   // <= 8700*136*8 B
    int* partial = (int*)mask;           // 8*8704*4 = 278KB, dead before mask written
    // diag (NPAD u64) aliases xyxy_in: last read of xyxy_in is rank_scatter;
    // diag written by nms_mask_row (later), read by the scan; next stage's
    // prep rewrites xyxy_in after the scan completes.
    uint64_t* diag = (uint64_t*)d_ws;

    // Stage 1: YOLO (stride = nch = 132)
    prep_yolo<<<(NY + 255) / 256, 256, 0, stream>>>(yolo, xyxy_in, conf_in, NY);
    run_stage(xyxy_in, conf_in, xyxy_s, conf_s, partial, mask, diag,
              NY, 132, stream, nullptr, xyxy_f, conf_f, 0);

    // Stage 2: RT-DETR (nch = 5, stride padded to 6)
    prep_rtdetr<<<1, 512, 0, stream>>>(rtdetr, xyxy_in, conf_in, NR);
    run_stage(xyxy_in, conf_in, xyxy_s, conf_s, partial, mask, diag,
              NR, 6, stream, nullptr, xyxy_f, conf_f, NY);

    // Stage 3: final over fused concat (stride = nch = 136)
    run_stage(xyxy_f, conf_f, xyxy_s, conf_s, partial, mask, diag,
              NF, 136, stream, out, nullptr, nullptr, 0);
}

// Round 13
// 329.415 us; speedup vs baseline: 1.2819x; 1.2819x over previous
//
#include <hip/hip_runtime.h>
#include <cstdint>
#include <cstddef>

#define NY 8400
#define NR 300
#define NF 8700
#define STHR 0.5f
#define ITHR 0.5f
#define NSPLIT 8
#define NPAD 8704
#define NCHMAX 136
#define WAVES 16
#define NCHPAD 137   // per-copy u64 stride (padded)

// IOU with explicit-rounding ops so fp-contraction cannot perturb the
// iou > 0.5 comparison vs the numpy fp32 reference.
__device__ __forceinline__ float iou_pair(float4 a, float4 b) {
    float ltx = fmaxf(a.x, b.x);
    float lty = fmaxf(a.y, b.y);
    float rbx = fminf(a.z, b.z);
    float rby = fminf(a.w, b.w);
    float w = fmaxf(__fsub_rn(rbx, ltx), 0.0f);
    float h = fmaxf(__fsub_rn(rby, lty), 0.0f);
    float inter  = __fmul_rn(w, h);
    float area_a = __fmul_rn(__fsub_rn(a.z, a.x), __fsub_rn(a.w, a.y));
    float area_b = __fmul_rn(__fsub_rn(b.z, b.x), __fsub_rn(b.w, b.y));
    float denom  = __fsub_rn(__fadd_rn(area_a, area_b), inter);
    float d = denom > 0.0f ? denom : 1.0f;
    return __fdiv_rn(inter, d);
}

__device__ __forceinline__ uint64_t readlane64(uint64_t v, int k) {
    uint32_t lo = (uint32_t)__builtin_amdgcn_readlane((int)(uint32_t)v, k);
    uint32_t hi = (uint32_t)__builtin_amdgcn_readlane((int)(uint32_t)(v >> 32), k);
    return ((uint64_t)hi << 32) | lo;
}

__device__ __forceinline__ uint64_t rfl64(uint64_t v) {
    uint32_t lo = (uint32_t)__builtin_amdgcn_readfirstlane((int)(uint32_t)v);
    uint32_t hi = (uint32_t)__builtin_amdgcn_readfirstlane((int)(uint32_t)(v >> 32));
    return ((uint64_t)hi << 32) | lo;
}

// ---------- Stage 1/3 rank (prep fused in; publishes nvalid) ----------

// YOLO variant: conf read straight from channel-major raw (1,5,8400).
__global__ void rank_partial_y(const float* __restrict__ y, int* __restrict__ partial,
                               int* __restrict__ nv, int N) {
    __shared__ float kk[1152];
    if (blockIdx.x == 0 && blockIdx.y == 0 && threadIdx.x == 0) *nv = 0;
    int i  = blockIdx.x * 256 + threadIdx.x;
    int js = blockIdx.y;
    int slice = (N + NSPLIT - 1) / NSPLIT;
    int j0 = js * slice;
    int j1 = min(N, j0 + slice);
    for (int j = j0 + threadIdx.x; j < j1; j += 256) {
        float c = y[4 * N + j];
        kk[j - j0] = (c >= STHR) ? c : -1.0f;
    }
    __syncthreads();
    float ci = (i < N) ? y[4 * N + i] : 0.0f;
    float ki = (ci >= STHR) ? ci : -1.0f;
    int r = 0;
    int len = j1 - j0;
    for (int jj = 0; jj < len; ++jj) {
        float kj = kk[jj];
        int j = j0 + jj;
        r += (kj > ki) || (kj == ki && j < i);
    }
    if (i < N) partial[js * NPAD + i] = r;
}

__global__ void rank_scatter_y(const float* __restrict__ y, const int* __restrict__ partial,
                               float* __restrict__ xyxy_s, float* __restrict__ conf_s,
                               int* __restrict__ nv, int N) {
    int i = blockIdx.x * blockDim.x + threadIdx.x;
    int lane = threadIdx.x & 63;
    int vmax = 0;
    if (i < N) {
        float ci = y[4 * N + i];
        int rank = 0;
        #pragma unroll
        for (int js = 0; js < NSPLIT; ++js) rank += partial[js * NPAD + i];
        float cx = y[0 * N + i], cy = y[1 * N + i];
        float w  = y[2 * N + i], h  = y[3 * N + i];
        xyxy_s[rank * 4 + 0] = cx - w * 0.5f;
        xyxy_s[rank * 4 + 1] = cy - h * 0.5f;
        xyxy_s[rank * 4 + 2] = cx + w * 0.5f;
        xyxy_s[rank * 4 + 3] = cy + h * 0.5f;
        conf_s[rank] = ci;
        if (ci >= STHR) vmax = rank + 1;
    }
    #pragma unroll
    for (int s = 32; s > 0; s >>= 1) vmax = max(vmax, __shfl_down(vmax, s, 64));
    if (lane == 0 && vmax > 0) atomicMax(nv, vmax);
}

// Generic variant (stage 3: xyxy/conf arrays).
__global__ void rank_partial(const float* __restrict__ conf, int* __restrict__ partial,
                             int* __restrict__ nv, int N) {
    __shared__ float kk[1152];
    if (blockIdx.x == 0 && blockIdx.y == 0 && threadIdx.x == 0) *nv = 0;
    int i  = blockIdx.x * 256 + threadIdx.x;
    int js = blockIdx.y;
    int slice = (N + NSPLIT - 1) / NSPLIT;
    int j0 = js * slice;
    int j1 = min(N, j0 + slice);
    for (int j = j0 + threadIdx.x; j < j1; j += 256) {
        float c = conf[j];
        kk[j - j0] = (c >= STHR) ? c : -1.0f;
    }
    __syncthreads();
    float ci = (i < N) ? conf[i] : 0.0f;
    float ki = (ci >= STHR) ? ci : -1.0f;
    int r = 0;
    int len = j1 - j0;
    for (int jj = 0; jj < len; ++jj) {
        float kj = kk[jj];
        int j = j0 + jj;
        r += (kj > ki) || (kj == ki && j < i);
    }
    if (i < N) partial[js * NPAD + i] = r;
}

__global__ void rank_scatter(const float* __restrict__ xyxy, const float* __restrict__ conf,
                             const int* __restrict__ partial,
                             float* __restrict__ xyxy_s, float* __restrict__ conf_s,
                             int* __restrict__ nv, int N) {
    int i = blockIdx.x * blockDim.x + threadIdx.x;
    int lane = threadIdx.x & 63;
    int vmax = 0;
    if (i < N) {
        float ci = conf[i];
        int rank = 0;
        #pragma unroll
        for (int js = 0; js < NSPLIT; ++js) rank += partial[js * NPAD + i];
        xyxy_s[rank * 4 + 0] = xyxy[i * 4 + 0];
        xyxy_s[rank * 4 + 1] = xyxy[i * 4 + 1];
        xyxy_s[rank * 4 + 2] = xyxy[i * 4 + 2];
        xyxy_s[rank * 4 + 3] = xyxy[i * 4 + 3];
        conf_s[rank] = ci;
        if (ci >= STHR) vmax = rank + 1;
    }
    #pragma unroll
    for (int s = 32; s > 0; s >>= 1) vmax = max(vmax, __shfl_down(vmax, s, 64));
    if (lane == 0 && vmax > 0) atomicMax(nv, vmax);
}

// ---------- Mask build, nvalid-gated ----------
// Rows >= nvalid and chunks >= vch are provably never read by the scan
// (ISSUE's rok/pairok/tailok). Below-diag: only chunk cd-1 is read (straddling
// ulonglong2) -> zero just that one. ~6x less work than full triangle.
__global__ void nms_mask_row(const float* __restrict__ xyxy_s, uint64_t* __restrict__ mask,
                             uint64_t* __restrict__ diag, const int* __restrict__ nv,
                             int N, int stride) {
    int i = blockIdx.x;
    int nvalid = *nv;
    if (i >= nvalid) return;
    int vch = (nvalid + 63) >> 6;
    int lane = threadIdx.x & 63;
    int wv   = threadIdx.x >> 6;
    int cd = i >> 6;
    if (threadIdx.x == 0 && cd > 0) mask[(size_t)i * stride + cd - 1] = 0ull;
    float4 bi = *(const float4*)(xyxy_s + (size_t)i * 4);
    for (int c = cd + wv; c < vch; c += 4) {
        int j = (c << 6) + lane;
        bool bit = false;
        if (j < N && j > i) {
            float4 bj = *(const float4*)(xyxy_s + (size_t)j * 4);
            bit = iou_pair(bi, bj) > ITHR;
        }
        uint64_t m = __ballot(bit);
        if (lane == 0) {
            mask[(size_t)i * stride + c] = m;
            if (c == cd) diag[i] = m;
        }
    }
}

// ---------- Scan: EXACT round-10 validated version ----------
__global__ __launch_bounds__(1024, 1)
void nms_scan_mw(const float* __restrict__ conf_s, const uint64_t* __restrict__ mask,
                 const uint64_t* __restrict__ diag, const float* __restrict__ xyxy_s,
                 float* __restrict__ out5, float* __restrict__ xf, float* __restrict__ cf,
                 int off, int N, int nch, int stride) {
    __shared__ uint64_t bmflat[WAVES * NCHPAD];
    __shared__ uint64_t keptw[NCHMAX];
    __shared__ int redcnt[WAVES];

    int tid  = threadIdx.x;
    int wv   = tid >> 6;
    int lane = tid & 63;
    bool hastail = (128 + lane) < nch;

    for (int idx = tid; idx < WAVES * NCHPAD; idx += 1024) bmflat[idx] = 0ull;
    int cnt = 0;
    for (int j = tid; j < N; j += 1024) cnt += (conf_s[j] >= STHR) ? 1 : 0;
    #pragma unroll
    for (int s = 32; s > 0; s >>= 1) cnt += __shfl_down(cnt, s, 64);
    if (lane == 0) redcnt[wv] = cnt;
    __syncthreads();
    int nvalid = 0;
    #pragma unroll
    for (int q = 0; q < WAVES; ++q) nvalid += redcnt[q];

    int vch = (nvalid + 63) >> 6;

    ulonglong2 sA[4], sB[4];
    uint64_t tA[4] = {0,0,0,0}, tB[4] = {0,0,0,0};
    uint64_t dgA = 0, dgB = 0;
    #pragma unroll
    for (int q = 0; q < 4; ++q) { sA[q].x = sA[q].y = 0ull; sB[q].x = sB[q].y = 0ull; }

#define ISSUE(S, CW) do {                                                     \
    int _c = (CW);                                                            \
    if (_c < vch) {                                                           \
        int base = _c << 6;                                                   \
        dg##S = diag[base + lane];                                            \
        bool pairok = (2 * lane + 1 >= _c) && (2 * lane < vch);               \
        bool tailok = hastail && (128 + lane >= _c) && (128 + lane < vch);    \
        _Pragma("unroll")                                                     \
        for (int q = 0; q < 4; ++q) {                                         \
            int row = base + (wv << 2) + q;                                   \
            bool rok = row < nvalid;                                          \
            row = row < N ? row : N - 1;                                      \
            const uint64_t* rb = mask + (size_t)row * stride;                 \
            ulonglong2 v; v.x = 0ull; v.y = 0ull;                             \
            if (pairok && rok) v = *((const ulonglong2*)rb + lane);           \
            s##S[q] = v;                                                      \
            t##S[q] = (tailok && rok) ? rb[128 + lane] : 0ull;                \
        }                                                                     \
    }                                                                         \
} while (0)

#define RESOLVE(S, CW) do {                                                   \
    int _c = (CW);                                                            \
    if (_c < vch && wv == 0) {                                                \
        int base = _c << 6;                                                   \
        uint64_t curw_v = (base + 64 > nvalid)                                \
            ? ((nvalid > base) ? (~0ull << (nvalid - base)) : ~0ull) : 0ull;  \
        _Pragma("unroll")                                                     \
        for (int q = 0; q < WAVES; ++q) curw_v |= bmflat[q * NCHPAD + _c];    \
        uint64_t alive = ~rfl64(curw_v);                                      \
        uint64_t Sset = __ballot((dg##S & alive) != 0ull) & alive;            \
        uint64_t sup = 0ull;                                                  \
        while (Sset) {                                                        \
            int k = __builtin_amdgcn_readfirstlane((int)__builtin_ctzll(Sset)); \
            uint64_t rck = readlane64(dg##S, k);                              \
            if (!((sup >> k) & 1ull)) sup |= rck;                             \
            Sset &= Sset - 1;                                                 \
            Sset &= ~sup;                                                     \
        }                                                                     \
        uint64_t kept = alive & ~sup;                                         \
        if (lane == 0) keptw[_c] = kept;                                      \
    }                                                                         \
} while (0)

#define ORPH(S, CW) do {                                                      \
    int _c = (CW);                                                            \
    if (_c < vch) {                                                           \
        uint64_t kept = keptw[_c];                                            \
        uint64_t a0 = 0, a1 = 0, at = 0;                                      \
        _Pragma("unroll")                                                     \
        for (int q = 0; q < 4; ++q) {                                         \
            uint64_t mk = 0ull - ((kept >> ((wv << 2) + q)) & 1ull);          \
            a0 |= s##S[q].x & mk; a1 |= s##S[q].y & mk; at |= t##S[q] & mk;   \
        }                                                                     \
        bmflat[wv * NCHPAD + 2 * lane]     |= a0;                             \
        bmflat[wv * NCHPAD + 2 * lane + 1] |= a1;                             \
        if (hastail) bmflat[wv * NCHPAD + 128 + lane] |= at;                  \
    }                                                                         \
} while (0)

    ISSUE(A, 0);
    for (int c = 0; c < vch; c += 2) {
        __syncthreads();
        ISSUE(B, c + 1);
        RESOLVE(A, c);
        __syncthreads();
        ORPH(A, c);
        __syncthreads();
        ISSUE(A, c + 2);
        RESOLVE(B, c + 1);
        __syncthreads();
        ORPH(B, c + 1);
    }
#undef ISSUE
#undef RESOLVE
#undef ORPH

    __syncthreads();
    for (int j = tid; j < N; j += 1024) {
        int w = j >> 6;
        uint64_t kw = (w < vch) ? keptw[w] : 0ull;
        bool keep = (kw >> (j & 63)) & 1ull;
        float4 b = *(const float4*)(xyxy_s + (size_t)j * 4);
        float cv = conf_s[j];
        if (out5) {
            out5[j * 5 + 0] = keep ? b.x : 0.0f;
            out5[j * 5 + 1] = keep ? b.y : 0.0f;
            out5[j * 5 + 2] = keep ? b.z : 0.0f;
            out5[j * 5 + 3] = keep ? b.w : 0.0f;
            out5[j * 5 + 4] = keep ? cv  : 0.0f;
        } else {
            int o = off + j;
            xf[o * 4 + 0] = keep ? b.x : 0.0f;
            xf[o * 4 + 1] = keep ? b.y : 0.0f;
            xf[o * 4 + 2] = keep ? b.z : 0.0f;
            xf[o * 4 + 3] = keep ? b.w : 0.0f;
            cf[o] = keep ? cv : 0.0f;
        }
    }
}

// ---------- Stage 2 fully fused: one block, 300 boxes ----------
__global__ __launch_bounds__(512, 1)
void stage2_all(const float* __restrict__ r, float* __restrict__ xf, float* __restrict__ cf,
                int off) {
    __shared__ float redf[512];
    __shared__ float cn[NR];
    __shared__ float sxy[NR * 4];
    __shared__ float sconf[NR];
    __shared__ uint64_t smask[NR * 5];
    __shared__ uint64_t remw[5];
    __shared__ uint64_t keptw2[5];
    __shared__ int redi[8];

    int t = threadIdx.x, lane = t & 63, wv = t >> 6;

    // max-reduce conf
    float m = -INFINITY;
    for (int i = t; i < NR; i += 512) m = fmaxf(m, r[i * 5 + 4]);
    redf[t] = m;
    __syncthreads();
    for (int s = 256; s > 0; s >>= 1) {
        if (t < s) redf[t] = fmaxf(redf[t], redf[t + s]);
        __syncthreads();
    }
    float mx = redf[0];

    // normalized conf
    for (int i = t; i < NR; i += 512) cn[i] = __fdiv_rn(r[i * 5 + 4], mx);
    __syncthreads();

    // count valid
    int cnt = 0;
    for (int i = t; i < NR; i += 512) cnt += (cn[i] >= STHR) ? 1 : 0;
    #pragma unroll
    for (int s = 32; s > 0; s >>= 1) cnt += __shfl_down(cnt, s, 64);
    if (lane == 0) redi[wv] = cnt;

    // rank + scatter (box math identical to prep_rtdetr+cxcywh2xyxy)
    for (int i = t; i < NR; i += 512) {
        float ci = cn[i];
        float ki = (ci >= STHR) ? ci : -1.0f;
        int rk = 0;
        for (int j = 0; j < NR; ++j) {
            float cj = cn[j];
            float kj = (cj >= STHR) ? cj : -1.0f;
            rk += (kj > ki) || (kj == ki && j < i);
        }
        float cx = r[i * 5 + 0], cy = r[i * 5 + 1];
        float w  = r[i * 5 + 2], h  = r[i * 5 + 3];
        sxy[rk * 4 + 0] = cx - w * 0.5f;
        sxy[rk * 4 + 1] = cy - h * 0.5f;
        sxy[rk * 4 + 2] = cx + w * 0.5f;
        sxy[rk * 4 + 3] = cy + h * 0.5f;
        sconf[rk] = ci;
    }
    __syncthreads();
    int nvalid = 0;
    #pragma unroll
    for (int q = 0; q < 8; ++q) nvalid += redi[q];
    int vch = (nvalid + 63) >> 6;   // <= 5

    // init removed words
    if (t < 5) {
        int base = t << 6;
        uint64_t v = 0ull;
        if (base >= nvalid) v = ~0ull;
        else if (base + 64 > nvalid) v = (~0ull) << (nvalid - base);
        remw[t] = v;
    }

    // masks: wave wv handles rows wv, wv+8, ... (valid rows only)
    for (int i = wv; i < nvalid; i += 8) {
        float4 bi = make_float4(sxy[i * 4 + 0], sxy[i * 4 + 1], sxy[i * 4 + 2], sxy[i * 4 + 3]);
        int cd = i >> 6;
        for (int c = cd; c < vch; ++c) {
            int j = (c << 6) + lane;
            bool bit = false;
            if (j < NR && j > i) {
                float4 bj = make_float4(sxy[j * 4 + 0], sxy[j * 4 + 1], sxy[j * 4 + 2], sxy[j * 4 + 3]);
                bit = iou_pair(bi, bj) > ITHR;
            }
            uint64_t mm = __ballot(bit);
            if (lane == 0) smask[i * 5 + c] = mm;
        }
    }
    __syncthreads();

    // wave-0 serial scan (sparse resolve, same algebra as the big scan)
    if (wv == 0) {
        #pragma unroll
        for (int c = 0; c < 5; ++c) {
            if (c < vch) {
                int base = c << 6;
                int rowi = base + lane; if (rowi > NR - 1) rowi = NR - 1;
                uint64_t dg = smask[rowi * 5 + c];   // rows >= nvalid: garbage, masked by alive
                uint64_t curw = remw[c];
                uint64_t alive = ~rfl64(curw);
                uint64_t Sset = __ballot((dg & alive) != 0ull) & alive;
                uint64_t sup = 0ull;
                while (Sset) {
                    int k = __builtin_amdgcn_readfirstlane((int)__builtin_ctzll(Sset));
                    uint64_t rck = readlane64(dg, k);
                    if (!((sup >> k) & 1ull)) sup |= rck;
                    Sset &= Sset - 1;
                    Sset &= ~sup;
                }
                uint64_t kept = alive & ~sup;
                if (lane == 0) keptw2[c] = kept;
                // OR kept rows' later words into remw (lanes 1..4 parallel over words)
                uint64_t kk = rfl64(kept);
                while (kk) {
                    int k2 = __builtin_amdgcn_readfirstlane((int)__builtin_ctzll(kk));
                    kk &= kk - 1;
                    int row = base + k2;
                    if (lane > c && lane < vch) remw[lane] |= smask[row * 5 + lane];
                }
            }
        }
    }
    __syncthreads();

    // epilogue
    for (int j = t; j < NR; j += 512) {
        int w = j >> 6;
        uint64_t kw = (w < vch) ? keptw2[w] : 0ull;
        bool keep = (kw >> (j & 63)) & 1ull;
        int o = off + j;
        xf[o * 4 + 0] = keep ? sxy[j * 4 + 0] : 0.0f;
        xf[o * 4 + 1] = keep ? sxy[j * 4 + 1] : 0.0f;
        xf[o * 4 + 2] = keep ? sxy[j * 4 + 2] : 0.0f;
        xf[o * 4 + 3] = keep ? sxy[j * 4 + 3] : 0.0f;
        cf[o] = keep ? sconf[j] : 0.0f;
    }
}

extern "C" void kernel_launch(void* const* d_in, const int* in_sizes, int n_in,
                              void* d_out, int out_size, void* d_ws, size_t ws_size,
                              hipStream_t stream) {
    const float* yolo   = (const float*)d_in[0];  // (1,5,8400)
    const float* rtdetr = (const float*)d_in[1];  // (1,300,5)
    float* out = (float*)d_out;                   // (8700,5)
    float* ws  = (float*)d_ws;

    // ws layout (bytes):
    //   [0, 69632)        diag (NPAD u64)
    //   [174000, 313200)  xyxy_s (8700*4 f32, 16B aligned)
    //   [313200, 348000)  conf_s
    //   [348000, 487200)  xyxy_f (stage-3 input)
    //   [487200, 522000)  conf_f
    //   [522000, 522004)  nvalid
    //   [523088, ...)     mask (8700*136*8) ; partial aliases its head
    uint64_t* diag  = (uint64_t*)d_ws;
    float* xyxy_s   = ws + 43500;
    float* conf_s   = ws + 78300;
    float* xyxy_f   = ws + 87000;
    float* conf_f   = ws + 121800;
    int* nvalid_dev = (int*)((char*)d_ws + 522000);
    uint64_t* mask  = (uint64_t*)((char*)d_ws + 523088);
    int* partial    = (int*)mask;   // dead before mask is written

    // Stage 1: YOLO (stride = 132)
    {
        dim3 gA((NY + 255) / 256, NSPLIT);
        rank_partial_y<<<gA, 256, 0, stream>>>(yolo, partial, nvalid_dev, NY);
        rank_scatter_y<<<(NY + 255) / 256, 256, 0, stream>>>(yolo, partial, xyxy_s, conf_s, nvalid_dev, NY);
        nms_mask_row<<<NY, 256, 0, stream>>>(xyxy_s, mask, diag, nvalid_dev, NY, 132);
        nms_scan_mw<<<1, 1024, 0, stream>>>(conf_s, mask, diag, xyxy_s,
                                            nullptr, xyxy_f, conf_f, 0, NY, 132, 132);
    }

    // Stage 2: RT-DETR fully fused (writes rows [NY, NY+300) of xyxy_f/conf_f)
    stage2_all<<<1, 512, 0, stream>>>(rtdetr, xyxy_f, conf_f, NY);

    // Stage 3: final over fused concat (stride = 136)
    {
        dim3 gA((NF + 255) / 256, NSPLIT);
        rank_partial<<<gA, 256, 0, stream>>>(conf_f, partial, nvalid_dev, NF);
        rank_scatter<<<(NF + 255) / 256, 256, 0, stream>>>(xyxy_f, conf_f, partial, xyxy_s, conf_s, nvalid_dev, NF);
        nms_mask_row<<<NF, 256, 0, stream>>>(xyxy_s, mask, diag, nvalid_dev, NF, 136);
        nms_scan_mw<<<1, 1024, 0, stream>>>(conf_s, mask, diag, xyxy_s,
                                            out, nullptr, nullptr, 0, NF, 136, 136);
    }
}

// Round 14
// 242.691 us; speedup vs baseline: 1.7399x; 1.3573x over previous
//
#include <hip/hip_runtime.h>
#include <cstdint>
#include <cstddef>

#define NY 8400
#define NR 300
#define NF 8700
#define STHR 0.5f
#define ITHR 0.5f
#define NSPLIT 8
#define NPAD 8704
#define NCHMAX 136
#define GMAX 512

// IOU with explicit-rounding ops so fp-contraction cannot perturb the
// iou > 0.5 comparison vs the numpy fp32 reference.
__device__ __forceinline__ float iou_pair(float4 a, float4 b) {
    float ltx = fmaxf(a.x, b.x);
    float lty = fmaxf(a.y, b.y);
    float rbx = fminf(a.z, b.z);
    float rby = fminf(a.w, b.w);
    float w = fmaxf(__fsub_rn(rbx, ltx), 0.0f);
    float h = fmaxf(__fsub_rn(rby, lty), 0.0f);
    float inter  = __fmul_rn(w, h);
    float area_a = __fmul_rn(__fsub_rn(a.z, a.x), __fsub_rn(a.w, a.y));
    float area_b = __fmul_rn(__fsub_rn(b.z, b.x), __fsub_rn(b.w, b.y));
    float denom  = __fsub_rn(__fadd_rn(area_a, area_b), inter);
    float d = denom > 0.0f ? denom : 1.0f;
    return __fdiv_rn(inter, d);
}

__device__ __forceinline__ uint64_t readlane64(uint64_t v, int k) {
    uint32_t lo = (uint32_t)__builtin_amdgcn_readlane((int)(uint32_t)v, k);
    uint32_t hi = (uint32_t)__builtin_amdgcn_readlane((int)(uint32_t)(v >> 32), k);
    return ((uint64_t)hi << 32) | lo;
}

__device__ __forceinline__ uint64_t rfl64(uint64_t v) {
    uint32_t lo = (uint32_t)__builtin_amdgcn_readfirstlane((int)(uint32_t)v);
    uint32_t hi = (uint32_t)__builtin_amdgcn_readfirstlane((int)(uint32_t)(v >> 32));
    return ((uint64_t)hi << 32) | lo;
}

__device__ __forceinline__ uint64_t validword(int base, int nvalid) {
    if (base + 64 <= nvalid) return ~0ull;
    if (nvalid > base) return (1ull << (nvalid - base)) - 1ull;
    return 0ull;
}

// ---------- rank kernels (r13-validated; also zero colOR/seedOR) ----------
__global__ void rank_partial_y(const float* __restrict__ y, int* __restrict__ partial,
                               int* __restrict__ nv, uint64_t* __restrict__ colOR,
                               uint64_t* __restrict__ seedOR, int N) {
    __shared__ float kk[1152];
    if (blockIdx.x == 0 && blockIdx.y == 0) {
        if (threadIdx.x == 0) *nv = 0;
        if (threadIdx.x < NCHMAX) { colOR[threadIdx.x] = 0ull; seedOR[threadIdx.x] = 0ull; }
    }
    int i  = blockIdx.x * 256 + threadIdx.x;
    int js = blockIdx.y;
    int slice = (N + NSPLIT - 1) / NSPLIT;
    int j0 = js * slice;
    int j1 = min(N, j0 + slice);
    for (int j = j0 + threadIdx.x; j < j1; j += 256) {
        float c = y[4 * N + j];
        kk[j - j0] = (c >= STHR) ? c : -1.0f;
    }
    __syncthreads();
    float ci = (i < N) ? y[4 * N + i] : 0.0f;
    float ki = (ci >= STHR) ? ci : -1.0f;
    int r = 0;
    int len = j1 - j0;
    for (int jj = 0; jj < len; ++jj) {
        float kj = kk[jj];
        int j = j0 + jj;
        r += (kj > ki) || (kj == ki && j < i);
    }
    if (i < N) partial[js * NPAD + i] = r;
}

__global__ void rank_scatter_y(const float* __restrict__ y, const int* __restrict__ partial,
                               float* __restrict__ xyxy_s, float* __restrict__ conf_s,
                               int* __restrict__ nv, int N) {
    int i = blockIdx.x * blockDim.x + threadIdx.x;
    int lane = threadIdx.x & 63;
    int vmax = 0;
    if (i < N) {
        float ci = y[4 * N + i];
        int rank = 0;
        #pragma unroll
        for (int js = 0; js < NSPLIT; ++js) rank += partial[js * NPAD + i];
        float cx = y[0 * N + i], cy = y[1 * N + i];
        float w  = y[2 * N + i], h  = y[3 * N + i];
        xyxy_s[rank * 4 + 0] = cx - w * 0.5f;
        xyxy_s[rank * 4 + 1] = cy - h * 0.5f;
        xyxy_s[rank * 4 + 2] = cx + w * 0.5f;
        xyxy_s[rank * 4 + 3] = cy + h * 0.5f;
        conf_s[rank] = ci;
        if (ci >= STHR) vmax = rank + 1;
    }
    #pragma unroll
    for (int s = 32; s > 0; s >>= 1) vmax = max(vmax, __shfl_down(vmax, s, 64));
    if (lane == 0 && vmax > 0) atomicMax(nv, vmax);
}

__global__ void rank_partial(const float* __restrict__ conf, int* __restrict__ partial,
                             int* __restrict__ nv, uint64_t* __restrict__ colOR,
                             uint64_t* __restrict__ seedOR, int N) {
    __shared__ float kk[1152];
    if (blockIdx.x == 0 && blockIdx.y == 0) {
        if (threadIdx.x == 0) *nv = 0;
        if (threadIdx.x < NCHMAX) { colOR[threadIdx.x] = 0ull; seedOR[threadIdx.x] = 0ull; }
    }
    int i  = blockIdx.x * 256 + threadIdx.x;
    int js = blockIdx.y;
    int slice = (N + NSPLIT - 1) / NSPLIT;
    int j0 = js * slice;
    int j1 = min(N, j0 + slice);
    for (int j = j0 + threadIdx.x; j < j1; j += 256) {
        float c = conf[j];
        kk[j - j0] = (c >= STHR) ? c : -1.0f;
    }
    __syncthreads();
    float ci = (i < N) ? conf[i] : 0.0f;
    float ki = (ci >= STHR) ? ci : -1.0f;
    int r = 0;
    int len = j1 - j0;
    for (int jj = 0; jj < len; ++jj) {
        float kj = kk[jj];
        int j = j0 + jj;
        r += (kj > ki) || (kj == ki && j < i);
    }
    if (i < N) partial[js * NPAD + i] = r;
}

__global__ void rank_scatter(const float* __restrict__ xyxy, const float* __restrict__ conf,
                             const int* __restrict__ partial,
                             float* __restrict__ xyxy_s, float* __restrict__ conf_s,
                             int* __restrict__ nv, int N) {
    int i = blockIdx.x * blockDim.x + threadIdx.x;
    int lane = threadIdx.x & 63;
    int vmax = 0;
    if (i < N) {
        float ci = conf[i];
        int rank = 0;
        #pragma unroll
        for (int js = 0; js < NSPLIT; ++js) rank += partial[js * NPAD + i];
        xyxy_s[rank * 4 + 0] = xyxy[i * 4 + 0];
        xyxy_s[rank * 4 + 1] = xyxy[i * 4 + 1];
        xyxy_s[rank * 4 + 2] = xyxy[i * 4 + 2];
        xyxy_s[rank * 4 + 3] = xyxy[i * 4 + 3];
        conf_s[rank] = ci;
        if (ci >= STHR) vmax = rank + 1;
    }
    #pragma unroll
    for (int s = 32; s > 0; s >>= 1) vmax = max(vmax, __shfl_down(vmax, s, 64));
    if (lane == 0 && vmax > 0) atomicMax(nv, vmax);
}

// ---------- mask build (r13-validated, nvalid-gated) + colOR accumulation ----
__global__ void nms_mask_row(const float* __restrict__ xyxy_s, uint64_t* __restrict__ mask,
                             uint64_t* __restrict__ diag, uint64_t* __restrict__ colOR,
                             const int* __restrict__ nv, int N, int stride) {
    int i = blockIdx.x;
    int nvalid = *nv;
    if (i >= nvalid) return;
    int vch = (nvalid + 63) >> 6;
    int lane = threadIdx.x & 63;
    int wv   = threadIdx.x >> 6;
    int cd = i >> 6;
    if (threadIdx.x == 0 && cd > 0) mask[(size_t)i * stride + cd - 1] = 0ull;
    float4 bi = *(const float4*)(xyxy_s + (size_t)i * 4);
    for (int c = cd + wv; c < vch; c += 4) {
        int j = (c << 6) + lane;
        bool bit = false;
        if (j < N && j > i) {
            float4 bj = *(const float4*)(xyxy_s + (size_t)j * 4);
            bit = iou_pair(bi, bj) > ITHR;
        }
        uint64_t m = __ballot(bit);
        if (lane == 0) {
            mask[(size_t)i * stride + c] = m;
            if (c == cd) diag[i] = m;
            if (m) atomicOr((unsigned long long*)&colOR[c], (unsigned long long)m);
        }
    }
}

// ---------- seed pass: seed rows OR their mask rows into seedOR (parallel) ---
__global__ void seed_pass(const uint64_t* __restrict__ mask, const uint64_t* __restrict__ colOR,
                          uint64_t* __restrict__ seedOR, const int* __restrict__ nv, int stride) {
    int i = blockIdx.x;
    int nvalid = *nv;
    if (i >= nvalid) return;
    if ((colOR[i >> 6] >> (i & 63)) & 1ull) return;   // not a seed
    int vch = (nvalid + 63) >> 6;
    int cd = i >> 6;
    const uint64_t* rb = mask + (size_t)i * stride;
    for (int c = cd + threadIdx.x; c < vch; c += blockDim.x) {
        uint64_t m = rb[c];
        if (m) atomicOr((unsigned long long*)&seedOR[c], (unsigned long long)m);
    }
}

// ---------- finalize: seeds | greedy(gray); fallback full scan if G > GMAX ---
__global__ __launch_bounds__(1024, 1)
void nms_finalize(const float* __restrict__ xyxy_s,
                  const uint64_t* __restrict__ colOR, const uint64_t* __restrict__ seedOR,
                  const uint64_t* __restrict__ mask, const uint64_t* __restrict__ diag,
                  const int* __restrict__ nv, uint64_t* __restrict__ keptw_g,
                  int N, int nch, int stride) {
    __shared__ uint64_t keptw[NCHMAX];
    __shared__ int glist[GMAX];
    __shared__ uint64_t subm[GMAX * 8];   // 32 KB; fallback reuses as bitmap
    __shared__ uint64_t remg[8];
    __shared__ uint64_t kg[8];
    __shared__ int gcount_sh;

    int tid = threadIdx.x, wv = tid >> 6, lane = tid & 63;
    int nvalid = *nv;
    int vch = (nvalid + 63) >> 6;

    // init keptw = seed words (valid & ~colOR); 0 beyond vch
    for (int w = tid; w < nch; w += 1024) {
        uint64_t validw = validword(w << 6, nvalid);
        keptw[w] = (w < vch) ? (validw & ~colOR[w]) : 0ull;
    }
    __syncthreads();

    // compact gray indices (wave 0; lanes parallel per word)
    if (wv == 0) {
        int run = 0;
        for (int w = 0; w < vch; ++w) {
            int base = w << 6;
            uint64_t validw = validword(base, nvalid);
            uint64_t gw = rfl64(validw & colOR[w] & ~seedOR[w]);
            int myb = (int)((gw >> lane) & 1ull);
            int pos = run + (int)__popcll(gw & ((1ull << lane) - 1ull));
            if (myb && pos < GMAX) glist[pos] = base + lane;
            run += (int)__popcll(gw);
        }
        if (lane == 0) gcount_sh = run;
    }
    __syncthreads();
    int G = gcount_sh;

    if (G <= GMAX) {
        int gw8 = (G + 63) >> 6;   // <= 8
        // build gray sub-mask (same iou_pair bits as the big mask)
        for (int p = wv; p < G; p += 16) {
            int gi = glist[p];
            float4 bi = *(const float4*)(xyxy_s + (size_t)gi * 4);
            for (int qc = 0; qc < gw8; ++qc) {
                int q = (qc << 6) + lane;
                bool bit = false;
                if (q < G && q > p) {
                    int gj = glist[q];
                    float4 bj = *(const float4*)(xyxy_s + (size_t)gj * 4);
                    bit = iou_pair(bi, bj) > ITHR;
                }
                uint64_t mm = __ballot(bit);
                if (lane == 0) subm[p * 8 + qc] = mm;
            }
        }
        if (tid < 8) { remg[tid] = 0ull; kg[tid] = 0ull; }
        __syncthreads();

        // wave-0 greedy over gray (sparse resolve per 64-word)
        if (wv == 0) {
            for (int wc = 0; wc < gw8; ++wc) {
                int base = wc << 6;
                uint64_t validg = validword(base, G);
                uint64_t alive = validg & ~rfl64(remg[wc]);
                int rowi = base + lane; if (rowi >= GMAX) rowi = GMAX - 1;
                uint64_t dg = subm[rowi * 8 + wc];
                uint64_t Sset = __ballot((dg & alive) != 0ull) & alive;
                uint64_t sup = 0ull;
                while (Sset) {
                    int k = __builtin_amdgcn_readfirstlane((int)__builtin_ctzll(Sset));
                    uint64_t rck = readlane64(dg, k);
                    if (!((sup >> k) & 1ull)) sup |= rck;
                    Sset &= Sset - 1;
                    Sset &= ~sup;
                }
                uint64_t kept = alive & ~sup;
                if (lane == 0) kg[wc] = kept;
                uint64_t kk = rfl64(kept);
                while (kk) {
                    int k2 = __builtin_amdgcn_readfirstlane((int)__builtin_ctzll(kk));
                    kk &= kk - 1;
                    int row = base + k2;
                    if (lane > wc && lane < gw8) remg[lane] |= subm[row * 8 + lane];
                }
            }
            // scatter gray-kept back into keptw
            for (int wc = 0; wc < gw8; ++wc) {
                uint64_t kept = rfl64(kg[wc]);
                if ((kept >> lane) & 1ull) {
                    int idx = glist[(wc << 6) + lane];
                    atomicOr((unsigned long long*)&keptw[idx >> 6], 1ull << (idx & 63));
                }
            }
        }
        __syncthreads();
    } else {
        // FALLBACK (never expected for this data): sequential exact scan,
        // single shared bitmap (subm reused), LDS atomicOr. Slow but correct.
        uint64_t* remf = subm;
        for (int w = tid; w < NCHMAX; w += 1024) {
            if (w < vch) {
                int base = w << 6;
                remf[w] = (base + 64 <= nvalid) ? 0ull
                         : ((nvalid > base) ? ((~0ull) << (nvalid - base)) : ~0ull);
            } else remf[w] = ~0ull;
        }
        __syncthreads();
        for (int c = 0; c < vch; ++c) {
            if (wv == 0) {
                uint64_t alive = ~rfl64(remf[c]);
                int rowi = (c << 6) + lane;
                uint64_t dg = diag[rowi];          // rows >= nvalid garbage, masked by alive
                uint64_t Sset = __ballot((dg & alive) != 0ull) & alive;
                uint64_t sup = 0ull;
                while (Sset) {
                    int k = __builtin_amdgcn_readfirstlane((int)__builtin_ctzll(Sset));
                    uint64_t rck = readlane64(dg, k);
                    if (!((sup >> k) & 1ull)) sup |= rck;
                    Sset &= Sset - 1;
                    Sset &= ~sup;
                }
                uint64_t kept = alive & ~sup;
                if (lane == 0) keptw[c] = kept;
            }
            __syncthreads();
            uint64_t kept = keptw[c];
            for (int q = 0; q < 4; ++q) {
                int row = (c << 6) + (wv << 2) + q;
                if (row < nvalid && ((kept >> (row & 63)) & 1ull)) {
                    const uint64_t* rb = mask + (size_t)row * stride;
                    for (int cc = c + 1 + lane; cc < vch; cc += 64) {
                        uint64_t m = rb[cc];
                        if (m) atomicOr((unsigned long long*)&remf[cc], (unsigned long long)m);
                    }
                }
            }
            __syncthreads();
        }
    }

    __syncthreads();
    for (int w = tid; w < nch; w += 1024) keptw_g[w] = keptw[w];
}

// ---------- parallel epilogues (r2-validated pattern; keptw bit = keep) -----
__global__ void write_bs(const float* __restrict__ xyxy_s, const float* __restrict__ conf_s,
                         const uint64_t* __restrict__ keptw_g,
                         float* __restrict__ out, int N) {
    int j = blockIdx.x * blockDim.x + threadIdx.x;
    if (j >= N) return;
    bool keep = (keptw_g[j >> 6] >> (j & 63)) & 1ull;
    float4 b = *(const float4*)(xyxy_s + (size_t)j * 4);
    out[j * 5 + 0] = keep ? b.x : 0.0f;
    out[j * 5 + 1] = keep ? b.y : 0.0f;
    out[j * 5 + 2] = keep ? b.z : 0.0f;
    out[j * 5 + 3] = keep ? b.w : 0.0f;
    out[j * 5 + 4] = keep ? conf_s[j] : 0.0f;
}

__global__ void write_split(const float* __restrict__ xyxy_s, const float* __restrict__ conf_s,
                            const uint64_t* __restrict__ keptw_g,
                            float* __restrict__ xf, float* __restrict__ cf, int N, int off) {
    int j = blockIdx.x * blockDim.x + threadIdx.x;
    if (j >= N) return;
    bool keep = (keptw_g[j >> 6] >> (j & 63)) & 1ull;
    float4 b = *(const float4*)(xyxy_s + (size_t)j * 4);
    int o = off + j;
    xf[o * 4 + 0] = keep ? b.x : 0.0f;
    xf[o * 4 + 1] = keep ? b.y : 0.0f;
    xf[o * 4 + 2] = keep ? b.z : 0.0f;
    xf[o * 4 + 3] = keep ? b.w : 0.0f;
    cf[o] = keep ? conf_s[j] : 0.0f;
}

// ---------- stage 2: fully fused (r13-validated, unchanged) ----------
__global__ __launch_bounds__(512, 1)
void stage2_all(const float* __restrict__ r, float* __restrict__ xf, float* __restrict__ cf,
                int off) {
    __shared__ float redf[512];
    __shared__ float cn[NR];
    __shared__ float sxy[NR * 4];
    __shared__ float sconf[NR];
    __shared__ uint64_t smask[NR * 5];
    __shared__ uint64_t remw[5];
    __shared__ uint64_t keptw2[5];
    __shared__ int redi[8];

    int t = threadIdx.x, lane = t & 63, wv = t >> 6;

    float m = -INFINITY;
    for (int i = t; i < NR; i += 512) m = fmaxf(m, r[i * 5 + 4]);
    redf[t] = m;
    __syncthreads();
    for (int s = 256; s > 0; s >>= 1) {
        if (t < s) redf[t] = fmaxf(redf[t], redf[t + s]);
        __syncthreads();
    }
    float mx = redf[0];

    for (int i = t; i < NR; i += 512) cn[i] = __fdiv_rn(r[i * 5 + 4], mx);
    __syncthreads();

    int cnt = 0;
    for (int i = t; i < NR; i += 512) cnt += (cn[i] >= STHR) ? 1 : 0;
    #pragma unroll
    for (int s = 32; s > 0; s >>= 1) cnt += __shfl_down(cnt, s, 64);
    if (lane == 0) redi[wv] = cnt;

    for (int i = t; i < NR; i += 512) {
        float ci = cn[i];
        float ki = (ci >= STHR) ? ci : -1.0f;
        int rk = 0;
        for (int j = 0; j < NR; ++j) {
            float cj = cn[j];
            float kj = (cj >= STHR) ? cj : -1.0f;
            rk += (kj > ki) || (kj == ki && j < i);
        }
        float cx = r[i * 5 + 0], cy = r[i * 5 + 1];
        float w  = r[i * 5 + 2], h  = r[i * 5 + 3];
        sxy[rk * 4 + 0] = cx - w * 0.5f;
        sxy[rk * 4 + 1] = cy - h * 0.5f;
        sxy[rk * 4 + 2] = cx + w * 0.5f;
        sxy[rk * 4 + 3] = cy + h * 0.5f;
        sconf[rk] = ci;
    }
    __syncthreads();
    int nvalid = 0;
    #pragma unroll
    for (int q = 0; q < 8; ++q) nvalid += redi[q];
    int vch = (nvalid + 63) >> 6;

    if (t < 5) {
        int base = t << 6;
        uint64_t v = 0ull;
        if (base >= nvalid) v = ~0ull;
        else if (base + 64 > nvalid) v = (~0ull) << (nvalid - base);
        remw[t] = v;
    }

    for (int i = wv; i < nvalid; i += 8) {
        float4 bi = make_float4(sxy[i * 4 + 0], sxy[i * 4 + 1], sxy[i * 4 + 2], sxy[i * 4 + 3]);
        int cd = i >> 6;
        for (int c = cd; c < vch; ++c) {
            int j = (c << 6) + lane;
            bool bit = false;
            if (j < NR && j > i) {
                float4 bj = make_float4(sxy[j * 4 + 0], sxy[j * 4 + 1], sxy[j * 4 + 2], sxy[j * 4 + 3]);
                bit = iou_pair(bi, bj) > ITHR;
            }
            uint64_t mm = __ballot(bit);
            if (lane == 0) smask[i * 5 + c] = mm;
        }
    }
    __syncthreads();

    if (wv == 0) {
        #pragma unroll
        for (int c = 0; c < 5; ++c) {
            if (c < vch) {
                int base = c << 6;
                int rowi = base + lane; if (rowi > NR - 1) rowi = NR - 1;
                uint64_t dg = smask[rowi * 5 + c];
                uint64_t curw = remw[c];
                uint64_t alive = ~rfl64(curw);
                uint64_t Sset = __ballot((dg & alive) != 0ull) & alive;
                uint64_t sup = 0ull;
                while (Sset) {
                    int k = __builtin_amdgcn_readfirstlane((int)__builtin_ctzll(Sset));
                    uint64_t rck = readlane64(dg, k);
                    if (!((sup >> k) & 1ull)) sup |= rck;
                    Sset &= Sset - 1;
                    Sset &= ~sup;
                }
                uint64_t kept = alive & ~sup;
                if (lane == 0) keptw2[c] = kept;
                uint64_t kk = rfl64(kept);
                while (kk) {
                    int k2 = __builtin_amdgcn_readfirstlane((int)__builtin_ctzll(kk));
                    kk &= kk - 1;
                    int row = base + k2;
                    if (lane > c && lane < vch) remw[lane] |= smask[row * 5 + lane];
                }
            }
        }
    }
    __syncthreads();

    for (int j = t; j < NR; j += 512) {
        int w = j >> 6;
        uint64_t kw = (w < vch) ? keptw2[w] : 0ull;
        bool keep = (kw >> (j & 63)) & 1ull;
        int o = off + j;
        xf[o * 4 + 0] = keep ? sxy[j * 4 + 0] : 0.0f;
        xf[o * 4 + 1] = keep ? sxy[j * 4 + 1] : 0.0f;
        xf[o * 4 + 2] = keep ? sxy[j * 4 + 2] : 0.0f;
        xf[o * 4 + 3] = keep ? sxy[j * 4 + 3] : 0.0f;
        cf[o] = keep ? sconf[j] : 0.0f;
    }
}

extern "C" void kernel_launch(void* const* d_in, const int* in_sizes, int n_in,
                              void* d_out, int out_size, void* d_ws, size_t ws_size,
                              hipStream_t stream) {
    const float* yolo   = (const float*)d_in[0];  // (1,5,8400)
    const float* rtdetr = (const float*)d_in[1];  // (1,300,5)
    float* out = (float*)d_out;                   // (8700,5)
    float* ws  = (float*)d_ws;

    // ws layout (bytes):
    //   [0, 69632)        diag (NPAD u64)
    //   [69632, 70720)    colOR (136 u64)
    //   [70720, 71808)    seedOR (136 u64)
    //   [71808, 72896)    keptw_g (136 u64)
    //   [174000, 313200)  xyxy_s ; [313200,348000) conf_s
    //   [348000, 487200)  xyxy_f ; [487200,522000) conf_f
    //   [522000, 522004)  nvalid
    //   [523088, ...)     mask ; partial aliases its head
    uint64_t* diag    = (uint64_t*)d_ws;
    uint64_t* colOR   = (uint64_t*)((char*)d_ws + 69632);
    uint64_t* seedOR  = (uint64_t*)((char*)d_ws + 70720);
    uint64_t* keptw_g = (uint64_t*)((char*)d_ws + 71808);
    float* xyxy_s   = ws + 43500;
    float* conf_s   = ws + 78300;
    float* xyxy_f   = ws + 87000;
    float* conf_f   = ws + 121800;
    int* nvalid_dev = (int*)((char*)d_ws + 522000);
    uint64_t* mask  = (uint64_t*)((char*)d_ws + 523088);
    int* partial    = (int*)mask;

    // Stage 1: YOLO (stride = 132)
    {
        dim3 gA((NY + 255) / 256, NSPLIT);
        rank_partial_y<<<gA, 256, 0, stream>>>(yolo, partial, nvalid_dev, colOR, seedOR, NY);
        rank_scatter_y<<<(NY + 255) / 256, 256, 0, stream>>>(yolo, partial, xyxy_s, conf_s, nvalid_dev, NY);
        nms_mask_row<<<NY, 256, 0, stream>>>(xyxy_s, mask, diag, colOR, nvalid_dev, NY, 132);
        seed_pass<<<NY, 128, 0, stream>>>(mask, colOR, seedOR, nvalid_dev, 132);
        nms_finalize<<<1, 1024, 0, stream>>>(xyxy_s, colOR, seedOR, mask, diag,
                                             nvalid_dev, keptw_g, NY, 132, 132);
        write_split<<<(NY + 255) / 256, 256, 0, stream>>>(xyxy_s, conf_s, keptw_g, xyxy_f, conf_f, NY, 0);
    }

    // Stage 2: RT-DETR fully fused
    stage2_all<<<1, 512, 0, stream>>>(rtdetr, xyxy_f, conf_f, NY);

    // Stage 3: final (stride = 136)
    {
        dim3 gA((NF + 255) / 256, NSPLIT);
        rank_partial<<<gA, 256, 0, stream>>>(conf_f, partial, nvalid_dev, colOR, seedOR, NF);
        rank_scatter<<<(NF + 255) / 256, 256, 0, stream>>>(xyxy_f, conf_f, partial, xyxy_s, conf_s, nvalid_dev, NF);
        nms_mask_row<<<NF, 256, 0, stream>>>(xyxy_s, mask, diag, colOR, nvalid_dev, NF, 136);
        seed_pass<<<NF, 128, 0, stream>>>(mask, colOR, seedOR, nvalid_dev, 136);
        nms_finalize<<<1, 1024, 0, stream>>>(xyxy_s, colOR, seedOR, mask, diag,
                                             nvalid_dev, keptw_g, NF, 136, 136);
        write_bs<<<(NF + 255) / 256, 256, 0, stream>>>(xyxy_s, conf_s, keptw_g, out, NF);
    }
}